// Round 6
// baseline (413.410 us; speedup 1.0000x reference)
//
#include <hip/hip_runtime.h>

// NNMF fused: B=8192, NIN=3072, NOUT=512, 5 iterations.
// R12: SS=2 super-slots + h-master in LDS.
//  R11 rocprof (255 us main, 5100 cy/slot): W L2 stream ~2340 cy, LDS ~1450
//  + 540 conflict cy, VALU ~1200, MFMA ~940; busy sums to 42% -> ~58% stall.
//  Half of LDS traffic was Phase A's 8x-redundant h reads (every wave reads
//  the whole 16KB h tile every slot = 128 KB/block/slot).
//  Fix: one Phase-A h-read now feeds TWO kout-slots (for c: ha(c) -> MFMA
//  with w1A[c] and w1B[c]) -> h traffic and barriers both halve; each
//  barrier region has 2x MFMA/load work to overlap the W stream.
//  Register economy (VGPR=128 is immovable, R9/R10): fp32 h master moved
//  from 32 regs to LDS (boundary-only access, zero numerics change);
//  Phase A split into m=0/m=1 passes (16 acc regs live, released into r
//  immediately); w1A/w1B prefetched in region 2 (R11's proven pattern).
//  x pre-scaled x16 in prep (exact, power of 2).

#define NIN 3072
#define NOUT 512

using f32x4 = __attribute__((ext_vector_type(4))) float;
using i32x8 = __attribute__((ext_vector_type(8))) int;

union frag32 { i32x8 v; uint4 q[2]; };

#define MFMA128(A, B, C) \
    __builtin_amdgcn_mfma_scale_f32_16x16x128_f8f6f4( \
        (A), (B), (C), 0, 0, 0, (int)0x7f7f7f7f, 0, (int)0x7f7f7f7f)

__device__ __forceinline__ unsigned short f2bf(float f) {
    unsigned int u = __builtin_bit_cast(unsigned int, f);
    return (unsigned short)((u + 0x7fffu + ((u >> 16) & 1u)) >> 16);  // RNE
}
__device__ __forceinline__ float bf2f(unsigned short s) {
    unsigned int u = ((unsigned int)s) << 16;
    return __builtin_bit_cast(float, u);
}

// LDS-only barrier: cross-wave deps in the slot loop are LDS-only; global
// prefetches stay in flight (consumed by issuing wave, compiler inserts vmcnt).
#define LDS_BARRIER() do {                                   \
    asm volatile("s_waitcnt lgkmcnt(0)" ::: "memory");       \
    __builtin_amdgcn_s_barrier();                            \
    asm volatile("" ::: "memory");                           \
} while (0)

// ---------------------------------------------------------------------------
// prep_all: one launch, 8672 blocks x 256 threads.
//   blocks [0,8192)     : per-row x normalize (x16 pre-scale) -> bf16 X2
//   blocks [8192,8576)  : W -> W2 / W1 (fp8 e4m3, x4096, K=128 frag layout)
//   blocks [8576,8672)  : d0inv[k] = 1/(sum_n h0[n]*W[n][k] + 1e-20)
// K=128 fragment layouts (lane l holds 32 contiguous contraction elements,
// k = (l>>4)*32 + j):
//   W2 (Phase B B-op): addr = ((s*32 + w*4 + nt)*64 + l)*32 + j
//     element: n = w*64 + nt*16 + (l&15), k = s*128 + (l>>4)*32 + j
//   W1 (Phase A B-op): addr = (((s*8 + w)*4 + c)*64 + l)*32 + j
//     element: kout = s*128 + w*16 + (l&15), n = c*128 + (l>>4)*32 + j
// ---------------------------------------------------------------------------
__global__ void prep_all(const float* __restrict__ x,
                         const float* __restrict__ W,
                         const float* __restrict__ h_init,
                         unsigned short* __restrict__ X2,
                         unsigned char* __restrict__ W1,
                         unsigned char* __restrict__ W2,
                         float* __restrict__ d0inv) {
    __shared__ float wsum[4];
    __shared__ float dred[8][32];
    const int bb = blockIdx.x;
    const int t  = threadIdx.x;

    if (bb < 8192) {
        // ---- x row normalize -> bf16, pre-scaled x16 (exact: power of 2)
        const int b = bb;
        const float4* r4 = reinterpret_cast<const float4*>(x + (size_t)b * NIN);
        float s = 0.f;
        float4 v0 = r4[t], v1 = r4[t + 256], v2 = r4[t + 512];
        s = v0.x + v0.y + v0.z + v0.w + v1.x + v1.y + v1.z + v1.w + v2.x + v2.y + v2.z + v2.w;
        #pragma unroll
        for (int off = 32; off > 0; off >>= 1) s += __shfl_down(s, off, 64);
        int w = t >> 6, l = t & 63;
        if (l == 0) wsum[w] = s;
        __syncthreads();
        float inv = 16.0f / (wsum[0] + wsum[1] + wsum[2] + wsum[3] + 1e-20f);
        unsigned short* orow = X2 + (size_t)b * NIN;
        #pragma unroll
        for (int c = 0; c < 3; ++c) {
            float4 v = (c == 0) ? v0 : (c == 1) ? v1 : v2;
            ushort4 o;
            o.x = f2bf(v.x * inv); o.y = f2bf(v.y * inv);
            o.z = f2bf(v.z * inv); o.w = f2bf(v.w * inv);
            *reinterpret_cast<ushort4*>(orow + (t + c * 256) * 4) = o;
        }
    } else if (bb < 8192 + 384) {
        // ---- W quantization, K=128 frag layouts (32 B per thread)
        int tt = (bb - 8192) * 256 + t;       // 0 .. 98303
        unsigned int words[8];
        if (tt < 49152) {
            // W2: g = s*32 + w*4 + nt
            int l = tt & 63, g = tt >> 6;
            int s = g >> 5, rem = g & 31, w = rem >> 2, nt = rem & 3;
            int n = w * 64 + nt * 16 + (l & 15);
            int kbase = s * 128 + ((l >> 4) << 5);
            const float* src = W + (size_t)n * NIN + kbase;
            #pragma unroll
            for (int q = 0; q < 8; ++q) {
                float v0 = src[q * 4 + 0] * 4096.0f, v1 = src[q * 4 + 1] * 4096.0f;
                float v2 = src[q * 4 + 2] * 4096.0f, v3 = src[q * 4 + 3] * 4096.0f;
                int pk = __builtin_amdgcn_cvt_pk_fp8_f32(v0, v1, 0, false);
                pk     = __builtin_amdgcn_cvt_pk_fp8_f32(v2, v3, pk, true);
                words[q] = (unsigned int)pk;
            }
            uint4* dst = reinterpret_cast<uint4*>(W2 + (size_t)tt * 32);
            dst[0] = *reinterpret_cast<uint4*>(&words[0]);
            dst[1] = *reinterpret_cast<uint4*>(&words[4]);
        } else {
            // W1: g = (s*8 + w)*4 + c
            int u = tt - 49152;
            int l = u & 63, g = u >> 6;
            int c = g & 3, sw = g >> 2;
            int w = sw & 7, s = sw >> 3;
            int kout = s * 128 + w * 16 + (l & 15);
            int nbase = c * 128 + ((l >> 4) << 5);
            #pragma unroll
            for (int q = 0; q < 8; ++q) {
                float v0 = W[(size_t)(nbase + q * 4 + 0) * NIN + kout] * 4096.0f;
                float v1 = W[(size_t)(nbase + q * 4 + 1) * NIN + kout] * 4096.0f;
                float v2 = W[(size_t)(nbase + q * 4 + 2) * NIN + kout] * 4096.0f;
                float v3 = W[(size_t)(nbase + q * 4 + 3) * NIN + kout] * 4096.0f;
                int pk = __builtin_amdgcn_cvt_pk_fp8_f32(v0, v1, 0, false);
                pk     = __builtin_amdgcn_cvt_pk_fp8_f32(v2, v3, pk, true);
                words[q] = (unsigned int)pk;
            }
            uint4* dst = reinterpret_cast<uint4*>(W1 + (size_t)u * 32);
            dst[0] = *reinterpret_cast<uint4*>(&words[0]);
            dst[1] = *reinterpret_cast<uint4*>(&words[4]);
        }
    } else {
        // ---- d0inv: block owns 32 k-cols; thread (kid = t&31, nsub = t>>5)
        int kb = bb - 8576;                   // 0..95
        int kid = t & 31, nsub = t >> 5;      // 8 n-chunks of 64
        int k = kb * 32 + kid;
        int n0 = nsub * 64;
        float s = 0.f;
        const float* p = W + (size_t)n0 * NIN + k;
        #pragma unroll 8
        for (int n = 0; n < 64; ++n) s += h_init[n0 + n] * p[(size_t)n * NIN];
        dred[nsub][kid] = s;
        __syncthreads();
        if (t < 32) {
            float sm = 1e-20f;
            #pragma unroll
            for (int j = 0; j < 8; ++j) sm += dred[j][t];
            d0inv[kb * 32 + t] = 1.0f / sm;
        }
    }
}

// ---------------------------------------------------------------------------
// Main kernel. 256 blocks x 512 threads (8 waves), 32 rows/block, 1 block/CU.
// SS=2 super-slots (12/iter), 2 barriers per super-slot, MX K=128 fp8 MFMA.
// ---------------------------------------------------------------------------
__global__ __launch_bounds__(512, 1) void nnmf_main(
    const unsigned short* __restrict__ X2,
    const unsigned char* __restrict__ W1,
    const unsigned char* __restrict__ W2,
    const float* __restrict__ d0inv,
    const float* __restrict__ h_init,
    float* __restrict__ out)
{
    __shared__ unsigned char  h8_lds[32 * 528];      // 16.9 KB (fp8 h, x256)
    __shared__ float          h32_lds[32 * 516];     // 66.0 KB (fp32 h master)
    __shared__ unsigned short x_lds[2][32 * 136];    // 17.4 KB (two slots)
    __shared__ unsigned char  r8_lds[2][32 * 144];   //  9.2 KB (two slots)
    __shared__ float red[8][32];
    // total ~110.6 KB -> 1 block/CU (grid is 1/CU anyway)

    const int tid = threadIdx.x;
    const int w  = tid >> 6;        // wave 0..7
    const int l  = tid & 63;
    const int lo = l & 15;
    const int hi = l >> 4;          // 0..3
    const int b0 = blockIdx.x * 32;

    // fp32 h master init (each (row,col) owned by exactly one thread later)
    for (int idx = tid; idx < 32 * 512; idx += 512) {
        int r = idx >> 9, c = idx & 511;
        h32_lds[r * 516 + c] = h_init[c];
    }

    // x staging: thread -> (row, 16B chunk)
    const int xrow = tid >> 4, xcc = tid & 15;
    const uint4* xg = reinterpret_cast<const uint4*>(X2 + (size_t)(b0 + xrow) * NIN + xcc * 8);
    const int xoff = xrow * 136 + xcc * 8;

    // W base pointers (fp8, K=128 frag layouts; 32-B aligned per lane)
    const unsigned char* w1base = W1 + (size_t)w * 8192 + (size_t)l * 32;   // +s*65536 +c*2048
    const unsigned char* w2base = W2 + ((size_t)(w * 4) * 64 + l) * 32;     // +s*65536 +nt*2048

    // prime: x(0),x(1) -> LDS; issue x(2),x(3)
    *reinterpret_cast<uint4*>(&x_lds[0][xoff]) = xg[0];
    *reinterpret_cast<uint4*>(&x_lds[1][xoff]) = xg[16];
    uint4 xnA = xg[32], xnB = xg[48];
    frag32 w1A[4], w1B[4];          // valid from it0 t==11 region 2 on
    __syncthreads();

    const float DSCL = 9.5367431640625e-07f;  // 2^-20: undo h x256 * W1 x4096
    const float TS   = 1.0f / 65536.0f;       // undo W2 x4096 and x-r x16 scales
    f32x4 tacc[2][4];

    for (int it = 0; it < 5; ++it) {
        #pragma unroll
        for (int m = 0; m < 2; ++m)
            #pragma unroll
            for (int nt = 0; nt < 4; ++nt)
                tacc[m][nt] = (f32x4){0.f, 0.f, 0.f, 0.f};

        for (int t = 0; t < 12; ++t) {
            const int s = 2 * t;

            // =================== region 1: Phase A + r for both sub-slots
            float dvA = 0.f, dvB = 0.f;
            if (it == 0) {
                dvA = d0inv[s * 128 + w * 16 + lo];
                dvB = d0inv[(s + 1) * 128 + w * 16 + lo];
            }

            // ---- Phase A, rows m=0 (one h-read feeds BOTH sub-slots)
            f32x4 dA0 = {0,0,0,0}, dB0 = {0,0,0,0};
            if (it != 0) {
                #pragma unroll
                for (int c = 0; c < 4; ++c) {
                    frag32 ha;
                    const uint4* p = reinterpret_cast<const uint4*>(
                        &h8_lds[lo * 528 + c * 128 + hi * 32]);
                    ha.q[0] = p[0]; ha.q[1] = p[1];
                    dA0 = MFMA128(ha.v, w1A[c].v, dA0);
                    dB0 = MFMA128(ha.v, w1B[c].v, dB0);
                }
            }
            // ---- r rows 0-15 for both sub-slots (releases dA0/dB0)
            #pragma unroll
            for (int i = 0; i < 4; ++i) {
                int row0 = hi * 4 + i;
                float xA = bf2f(x_lds[0][row0 * 136 + w * 16 + lo]);  // pre-scaled x16
                float xB = bf2f(x_lds[1][row0 * 136 + w * 16 + lo]);
                float rA, rB;
                if (it == 0) { rA = xA * dvA; rB = xB * dvB; }
                else {
                    rA = xA * __builtin_amdgcn_rcpf(fmaf(dA0[i], DSCL, 1e-20f));
                    rB = xB * __builtin_amdgcn_rcpf(fmaf(dB0[i], DSCL, 1e-20f));
                }
                int cA = __builtin_amdgcn_cvt_pk_fp8_f32(rA, rA, 0, false);
                int cB = __builtin_amdgcn_cvt_pk_fp8_f32(rB, rB, 0, false);
                r8_lds[0][row0 * 144 + w * 16 + lo] = (unsigned char)(cA & 0xff);
                r8_lds[1][row0 * 144 + w * 16 + lo] = (unsigned char)(cB & 0xff);
            }

            // ---- Phase A, rows m=1
            f32x4 dA1 = {0,0,0,0}, dB1 = {0,0,0,0};
            if (it != 0) {
                #pragma unroll
                for (int c = 0; c < 4; ++c) {
                    frag32 ha;
                    const uint4* p = reinterpret_cast<const uint4*>(
                        &h8_lds[(16 + lo) * 528 + c * 128 + hi * 32]);
                    ha.q[0] = p[0]; ha.q[1] = p[1];
                    dA1 = MFMA128(ha.v, w1A[c].v, dA1);
                    dB1 = MFMA128(ha.v, w1B[c].v, dB1);
                }
            }

            // ---- issue w2vA (W2[s]) -- covered by r m=1 + barrier drain
            frag32 w2vA[4];
            {
                const unsigned char* w2p = w2base + (size_t)s * 65536;
                #pragma unroll
                for (int nt = 0; nt < 4; ++nt) {
                    const uint4* p = reinterpret_cast<const uint4*>(w2p + nt * 2048);
                    w2vA[nt].q[0] = p[0];
                    w2vA[nt].q[1] = p[1];
                }
            }

            // ---- r rows 16-31 for both sub-slots
            #pragma unroll
            for (int i = 0; i < 4; ++i) {
                int row1 = 16 + hi * 4 + i;
                float xA = bf2f(x_lds[0][row1 * 136 + w * 16 + lo]);
                float xB = bf2f(x_lds[1][row1 * 136 + w * 16 + lo]);
                float rA, rB;
                if (it == 0) { rA = xA * dvA; rB = xB * dvB; }
                else {
                    rA = xA * __builtin_amdgcn_rcpf(fmaf(dA1[i], DSCL, 1e-20f));
                    rB = xB * __builtin_amdgcn_rcpf(fmaf(dB1[i], DSCL, 1e-20f));
                }
                int cA = __builtin_amdgcn_cvt_pk_fp8_f32(rA, rA, 0, false);
                int cB = __builtin_amdgcn_cvt_pk_fp8_f32(rB, rB, 0, false);
                r8_lds[0][row1 * 144 + w * 16 + lo] = (unsigned char)(cA & 0xff);
                r8_lds[1][row1 * 144 + w * 16 + lo] = (unsigned char)(cB & 0xff);
            }
            LDS_BARRIER();   // barrier A

            // =================== region 2: Phase B both sub-slots + prefetch
            // ---- B(s): r8[0] x w2vA
            {
                frag32 ra0, ra1;
                const uint4* p0 = reinterpret_cast<const uint4*>(&r8_lds[0][lo * 144 + hi * 32]);
                const uint4* p1 = reinterpret_cast<const uint4*>(&r8_lds[0][(16 + lo) * 144 + hi * 32]);
                ra0.q[0] = p0[0]; ra0.q[1] = p0[1];
                ra1.q[0] = p1[0]; ra1.q[1] = p1[1];
                #pragma unroll
                for (int nt = 0; nt < 4; ++nt) {
                    tacc[0][nt] = MFMA128(ra0.v, w2vA[nt].v, tacc[0][nt]);
                    tacc[1][nt] = MFMA128(ra1.v, w2vA[nt].v, tacc[1][nt]);
                }
            }

            // ---- issue w2vB (W2[s+1]) + w1A for next super-slot
            frag32 w2vB[4];
            {
                const unsigned char* w2p = w2base + (size_t)(s + 1) * 65536;
                #pragma unroll
                for (int nt = 0; nt < 4; ++nt) {
                    const uint4* p = reinterpret_cast<const uint4*>(w2p + nt * 2048);
                    w2vB[nt].q[0] = p[0];
                    w2vB[nt].q[1] = p[1];
                }
            }
            if (it > 0 || t == 11) {
                int sw = (t == 11) ? 0 : s + 2;
                const unsigned char* w1p = w1base + (size_t)sw * 65536;
                #pragma unroll
                for (int c = 0; c < 4; ++c) {
                    const uint4* p = reinterpret_cast<const uint4*>(w1p + c * 2048);
                    w1A[c].q[0] = p[0];
                    w1A[c].q[1] = p[1];
                }
            }

            // ---- B(s+1): r8[1] x w2vB
            {
                frag32 ra0, ra1;
                const uint4* p0 = reinterpret_cast<const uint4*>(&r8_lds[1][lo * 144 + hi * 32]);
                const uint4* p1 = reinterpret_cast<const uint4*>(&r8_lds[1][(16 + lo) * 144 + hi * 32]);
                ra0.q[0] = p0[0]; ra0.q[1] = p0[1];
                ra1.q[0] = p1[0]; ra1.q[1] = p1[1];
                #pragma unroll
                for (int nt = 0; nt < 4; ++nt) {
                    tacc[0][nt] = MFMA128(ra0.v, w2vB[nt].v, tacc[0][nt]);
                    tacc[1][nt] = MFMA128(ra1.v, w2vB[nt].v, tacc[1][nt]);
                }
            }

            // ---- w1B for next super-slot (used early region 1: keep last)
            if (it > 0 || t == 11) {
                int sw = (t == 11) ? 1 : s + 3;
                const unsigned char* w1p = w1base + (size_t)sw * 65536;
                #pragma unroll
                for (int c = 0; c < 4; ++c) {
                    const uint4* p = reinterpret_cast<const uint4*>(w1p + c * 2048);
                    w1B[c].q[0] = p[0];
                    w1B[c].q[1] = p[1];
                }
            }

            // ---- stage x(s+2),x(s+3); issue x(s+4),x(s+5)
            *reinterpret_cast<uint4*>(&x_lds[0][xoff]) = xnA;
            *reinterpret_cast<uint4*>(&x_lds[1][xoff]) = xnB;
            {
                int fA = s + 4; if (fA >= 24) fA -= 24;
                int fB = s + 5; if (fB >= 24) fB -= 24;
                xnA = xg[(size_t)fA * 16];
                xnB = xg[(size_t)fB * 16];
            }
            LDS_BARRIER();   // barrier B
        }

        // ---- boundary: h_new = normalize(h * (1 + t*2^-16)), fp32 via LDS master
        float hv_[2][4][4];
        float p[2][4];
        #pragma unroll
        for (int m = 0; m < 2; ++m)
            #pragma unroll
            for (int i = 0; i < 4; ++i) p[m][i] = 0.f;

        #pragma unroll
        for (int m = 0; m < 2; ++m)
            #pragma unroll
            for (int nt = 0; nt < 4; ++nt)
                #pragma unroll
                for (int i = 0; i < 4; ++i) {
                    int row = m * 16 + hi * 4 + i;
                    int col = w * 64 + nt * 16 + lo;
                    float hv = h32_lds[row * 516 + col];
                    float v = hv * (1.f + tacc[m][nt][i] * TS);  // EPSILON_0 = 1
                    hv_[m][nt][i] = v;
                    p[m][i] += v;
                }
        #pragma unroll
        for (int mask = 1; mask < 16; mask <<= 1)
            #pragma unroll
            for (int m = 0; m < 2; ++m)
                #pragma unroll
                for (int i = 0; i < 4; ++i)
                    p[m][i] += __shfl_xor(p[m][i], mask, 64);
        if (lo == 0) {
            #pragma unroll
            for (int m = 0; m < 2; ++m)
                #pragma unroll
                for (int i = 0; i < 4; ++i)
                    red[w][m * 16 + hi * 4 + i] = p[m][i];
        }
        __syncthreads();
        float inv[2][4];
        #pragma unroll
        for (int m = 0; m < 2; ++m)
            #pragma unroll
            for (int i = 0; i < 4; ++i) {
                int row = m * 16 + hi * 4 + i;
                float S = 0.f;
                #pragma unroll
                for (int ww = 0; ww < 8; ++ww) S += red[ww][row];
                inv[m][i] = 1.f / (S + 1e-20f);
            }

        if (it < 4) {
            #pragma unroll
            for (int m = 0; m < 2; ++m)
                #pragma unroll
                for (int nt = 0; nt < 4; ++nt)
                    #pragma unroll
                    for (int i = 0; i < 4; ++i) {
                        int row = m * 16 + hi * 4 + i;
                        int col = w * 64 + nt * 16 + lo;
                        float hv = hv_[m][nt][i] * inv[m][i];
                        h32_lds[row * 516 + col] = hv;
                        int c = __builtin_amdgcn_cvt_pk_fp8_f32(hv * 256.0f, hv * 256.0f, 0, false);
                        h8_lds[row * 528 + col] = (unsigned char)(c & 0xff);
                    }
            __syncthreads();
        } else {
            #pragma unroll
            for (int m = 0; m < 2; ++m)
                #pragma unroll
                for (int nt = 0; nt < 4; ++nt)
                    #pragma unroll
                    for (int i = 0; i < 4; ++i) {
                        int row = m * 16 + hi * 4 + i;
                        int col = w * 64 + nt * 16 + lo;
                        out[(size_t)(b0 + row) * 512 + col] = hv_[m][nt][i] * inv[m][i];
                    }
        }
    }
}

extern "C" void kernel_launch(void* const* d_in, const int* in_sizes, int n_in,
                              void* d_out, int out_size, void* d_ws, size_t ws_size,
                              hipStream_t stream) {
    const float* x   = (const float*)d_in[0];   // [8192][3072]
    const float* wgt = (const float*)d_in[1];   // [512][3072]
    const float* h0  = (const float*)d_in[2];   // [512]
    float* out = (float*)d_out;

    // ws: X2 bf16 50,331,648 | W1 fp8 1,572,864 | W2 fp8 1,572,864 | d0inv 12,288
    unsigned short* X2 = (unsigned short*)d_ws;
    unsigned char*  W1 = (unsigned char*)((char*)d_ws + 50331648);
    unsigned char*  W2 = (unsigned char*)((char*)d_ws + 51904512);
    float* d0inv       = (float*)((char*)d_ws + 53477376);

    prep_all<<<8672, 256, 0, stream>>>(x, wgt, h0, X2, W1, W2, d0inv);
    nnmf_main<<<256, 512, 0, stream>>>(X2, W1, W2, d0inv, h0, out);
}